// Round 2
// baseline (234.025 us; speedup 1.0000x reference)
//
#include <hip/hip_runtime.h>
#include <hip/hip_bf16.h>

// HypConvHyperboloid: B=32,H=64,W=64, C_IN=65, 3x3 edge-pad conv -> HCat(577) -> Lorentz FC(255) -> time restore
// M = 131072 pixels, K = 576 (bf16 MFMA) + 1 (t_cat fp32 rank-1 in epilogue), N = 255 (pad 256)
// Round 7: latency-bound diagnosis (MfmaUtil 17%, all pipes idle, 2 lockstep barrier domains/CU).
//          Keep the PROVEN round-5 2-phase schedule, change geometry: 256-thr blocks (4 waves),
//          tile 128x128 (N split in 2), 32.5KB LDS -> 4 blocks/CU = 4 independent barrier domains.
//          GEMM col n^ == out col n^ (col 0 = zero weight row) -> aligned f4 stores for both halves;
//          per-pixel partial sum(z^2) to ws; finalize_t writes t_out. Chunked XCD swizzle pairs the
//          two N-halves (+adjacent M-tiles) on one XCD L2 (A-halo + Wb sharing). prep_w merged into prep.

#define CLAMP63(v) ((v) < 0 ? 0 : ((v) > 63 ? 63 : (v)))

typedef __attribute__((ext_vector_type(8))) short short8;   // 8 bf16 = 4 VGPRs
typedef __attribute__((ext_vector_type(4))) float floatx4;  // C/D frag

__device__ __forceinline__ void gl2lds16(const void* g, void* l) {
  __builtin_amdgcn_global_load_lds(
      (const __attribute__((address_space(1))) void*)g,
      (__attribute__((address_space(3))) void*)l, 16, 0, 0);
}

// ---- merged prep: blocks [0,4096): x spatial -> bf16 pixel-major [pix][64]; col0 -> tsq = t^2
//                   blocks [4096,4352): W -> bf16 n-major [256][576] with row 0 ZERO (n^ = out col),
//                                       W col0 + b -> fp32 padded (entry 0 zero)
__global__ void prep(const float* __restrict__ x, const float* __restrict__ W,
                     const float* __restrict__ b,
                     __hip_bfloat16* __restrict__ xs, float* __restrict__ tsq,
                     __hip_bfloat16* __restrict__ Wb, float* __restrict__ Wt0,
                     float* __restrict__ bp) {
  if (blockIdx.x < 4096) {
    int idx = blockIdx.x * 256 + threadIdx.x;   // 1048576 = 131072 pix * 8 groups
    int p = idx >> 3, g = idx & 7;
    const float* src = x + (size_t)p * 65 + 1 + g * 8;
    __align__(16) __hip_bfloat16 tmp[8];
#pragma unroll
    for (int i = 0; i < 8; ++i) tmp[i] = __float2bfloat16(src[i]);
    *(short8*)(xs + (size_t)idx * 8) = *(const short8*)tmp;
    if (g == 0) { float t = x[(size_t)p * 65]; tsq[p] = t * t; }
  } else {
    int n = blockIdx.x - 4096;  // n^ in 0..255; n^>=1 maps to W row n^-1
    for (int k = threadIdx.x; k < 576; k += 256)
      Wb[n * 576 + k] = __float2bfloat16((n >= 1) ? W[(n - 1) * 577 + 1 + k] : 0.f);
    if (threadIdx.x == 0) {
      Wt0[n] = (n >= 1) ? W[(n - 1) * 577] : 0.f;
      bp[n]  = (n >= 1) ? b[n - 1] : 0.f;
    }
  }
}

// staging for one iteration: per wave, 2 A-chunks + 2 B-chunks (kg = w, m/n = j*64+lane).
// LDS A slot = kg*128 + m, B slot = kg*128 + n (16B slots); dests wave-uniform base (HW adds lane*16).
#define STAGE(IT, BUF)                                                            \
  do {                                                                            \
    const int nbr_ = (IT) >> 1;                                                   \
    const int dy_ = nbr_ / 3 - 1, dx_ = nbr_ % 3 - 1;                             \
    const int c0_ = ((IT) & 1) * 32;                                              \
    _Pragma("unroll")                                                             \
    for (int j = 0; j < 2; ++j) {                                                 \
      int y2_ = CLAMP63(a_by[j] + dy_);                                           \
      int x2_ = CLAMP63(a_bx[j] + dx_);                                           \
      gl2lds16(xs + (size_t)((a_bb[j] * 64 + y2_) * 64 + x2_) * 64 + c0_ + w * 8, \
               Ab + (BUF) * 4096 + w * 1024 + j * 512);                           \
      gl2lds16(b_src[j] + (IT) * 32,                                              \
               Bb + (BUF) * 4096 + w * 1024 + j * 512);                           \
    }                                                                             \
  } while (0)

// ---- main: M=128 x N=128 per block, BK=32, 18 iters, 4 waves (each 64x64), dbuf LDS (2-phase,
// compiler-scheduled). 32.5KB LDS + <=128 VGPR -> 4 blocks/CU (4 barrier domains).
__launch_bounds__(256, 4)
__global__ void hypconv_main(const float* __restrict__ tsq,
                             const __hip_bfloat16* __restrict__ xs,
                             const __hip_bfloat16* __restrict__ Wb,
                             const float* __restrict__ Wt0,
                             const float* __restrict__ bp,
                             float* __restrict__ out,
                             float* __restrict__ ssbuf) {
  __shared__ __align__(16) char smem[32768];  // A dbuf 16K + B dbuf 16K; reused: zbuf 32 x 132 f32
  __shared__ float tc_lds[128];
  ushort* Ab = (ushort*)smem;                 // 2 x 4096 ushort
  ushort* Bb = (ushort*)(smem + 16384);       // 2 x 4096 ushort
  float* zbuf = (float*)smem;                 // 32 rows x 132 f32 = 16896 B

  const int tid = threadIdx.x;
  const int w = tid >> 6, lane = tid & 63;
  const int quad = lane >> 4, ln = lane & 15;

  // chunked XCD swizzle: launch id L -> XCD L%8; logical = (L&7)*256 + (L>>3) gives each XCD a
  // contiguous logical chunk -> both nb-halves of an mb (and neighbor mbs) share one L2. 2048%8==0.
  const int lid = ((blockIdx.x & 7) << 8) + (blockIdx.x >> 3);
  const int mb = lid >> 1, nb = lid & 1;
  const int pix_base = mb * 128;
  const int m_off = (w >> 1) * 64, n_off = (w & 1) * 64;

  // A chunks j=0,1: pixel m = j*64+lane
  int a_bx[2], a_by[2], a_bb[2];
#pragma unroll
  for (int j = 0; j < 2; ++j) {
    int apix = pix_base + j * 64 + lane;
    a_bx[j] = apix & 63; a_by[j] = (apix >> 6) & 63; a_bb[j] = apix >> 12;
  }
  // B chunks j=0,1: row n^ = nb*128 + j*64 + lane, k-offset = w*8 (+ it*32 per iter)
  const __hip_bfloat16* b_src[2];
#pragma unroll
  for (int j = 0; j < 2; ++j)
    b_src[j] = Wb + (size_t)(nb * 128 + j * 64 + lane) * 576 + w * 8;

  floatx4 acc[4][4];
#pragma unroll
  for (int mf = 0; mf < 4; ++mf)
#pragma unroll
    for (int nf = 0; nf < 4; ++nf)
      acc[mf][nf] = (floatx4){0.f, 0.f, 0.f, 0.f};

  // t_cat first (tsq is 512 KB, L2-resident): its loads drain before staging begins,
  // keeping the vmcnt queue clean for the K-loop.
  if (tid < 128) {
    int pix = pix_base + tid;
    int bx = pix & 63, by = (pix >> 6) & 63, bb = pix >> 12;
    float s = 0.f;
#pragma unroll
    for (int dy = -1; dy <= 1; ++dy) {
      int y2 = CLAMP63(by + dy);
#pragma unroll
      for (int dx = -1; dx <= 1; ++dx) {
        int x2 = CLAMP63(bx + dx);
        s += tsq[(bb * 64 + y2) * 64 + x2];
      }
    }
    tc_lds[tid] = sqrtf(s - 8.0f);
  }

  STAGE(0, 0);  // prologue loads in flight

  for (int it = 0; it < 18; ++it) {
    __syncthreads();                 // buf(it&1) ready; prev frag reads done
    if (it < 17) STAGE(it + 1, (it + 1) & 1);   // prefetch overlaps frag reads + MFMA
    const ushort* Ar = Ab + (it & 1) * 4096;
    const ushort* Br = Bb + (it & 1) * 4096;
    short8 af[4], bfr[4];
#pragma unroll
    for (int mf = 0; mf < 4; ++mf)
      af[mf] = *(const short8*)&Ar[(quad * 128 + m_off + mf * 16 + ln) * 8];
#pragma unroll
    for (int nf = 0; nf < 4; ++nf)
      bfr[nf] = *(const short8*)&Br[(quad * 128 + n_off + nf * 16 + ln) * 8];
#pragma unroll
    for (int mf = 0; mf < 4; ++mf)
#pragma unroll
      for (int nf = 0; nf < 4; ++nf)
        acc[mf][nf] = __builtin_amdgcn_mfma_f32_16x16x32_bf16(af[mf], bfr[nf], acc[mf][nf], 0, 0, 0);
  }

  // ---- epilogue: z = acc + b[n^] + t_cat[m]*W0[n^]; LDS-staged (stride 132), aligned f4 stores.
  // Block's half-row ss partial -> ssbuf[nb*131072 + pix]; finalize_t writes t_out to col 0.
  __syncthreads();
  float wn[4], bnv[4];
#pragma unroll
  for (int nf = 0; nf < 4; ++nf) {
    int n = nb * 128 + n_off + nf * 16 + ln;
    wn[nf] = Wt0[n];
    bnv[nf] = bp[n];
  }

#pragma unroll
  for (int mf = 0; mf < 4; ++mf) {
    // stage 32 rows: lr = (w>>1)*16 + quad*4 + r ; local col = n_off + nf*16 + ln (0..127)
#pragma unroll
    for (int r = 0; r < 4; ++r) {
      float tcv = tc_lds[m_off + mf * 16 + quad * 4 + r];
      int lr = (w >> 1) * 16 + quad * 4 + r;
#pragma unroll
      for (int nf = 0; nf < 4; ++nf) {
        float z = acc[mf][nf][r] + bnv[nf] + tcv * wn[nf];
        zbuf[lr * 132 + n_off + nf * 16 + ln] = z;
      }
    }
    __syncthreads();
    // flush: 4 waves x 8 rows (half-wave per row); 32-lane butterfly for half-row ss
#pragma unroll
    for (int rr = 0; rr < 4; ++rr) {
      int lr = w * 8 + rr * 2 + (lane >> 5);
      float4 v = *(const float4*)&zbuf[lr * 132 + (lane & 31) * 4];
      float ss = v.x * v.x + v.y * v.y + v.z * v.z + v.w * v.w;  // n^=0 col is exactly 0
      ss += __shfl_xor(ss, 1, 64);
      ss += __shfl_xor(ss, 2, 64);
      ss += __shfl_xor(ss, 4, 64);
      ss += __shfl_xor(ss, 8, 64);
      ss += __shfl_xor(ss, 16, 64);
      int m = (lr >> 4) * 64 + mf * 16 + (lr & 15);
      *(float4*)&out[(size_t)(pix_base + m) * 256 + nb * 128 + (lane & 31) * 4] = v;
      if ((lane & 31) == 0) ssbuf[nb * 131072 + pix_base + m] = ss;
    }
    if (mf < 3) __syncthreads();  // protect zbuf before next chunk's staging
  }
}

// ---- finalize: t_out = sqrt(1 + ss0 + ss1) -> out[:, 0]
__global__ void finalize_t(const float* __restrict__ ssbuf, float* __restrict__ out) {
  int p = blockIdx.x * 256 + threadIdx.x;  // 131072
  out[(size_t)p * 256] = sqrtf(1.0f + ssbuf[p] + ssbuf[131072 + p]);
}

extern "C" void kernel_launch(void* const* d_in, const int* in_sizes, int n_in,
                              void* d_out, int out_size, void* d_ws, size_t ws_size,
                              hipStream_t stream) {
  const float* x = (const float*)d_in[0];   // (32,64,64,65)
  const float* W = (const float*)d_in[1];   // (255,577)
  const float* b = (const float*)d_in[2];   // (255,)
  float* out = (float*)d_out;               // (32,64,64,256)
  char* ws = (char*)d_ws;

  // workspace: xs 16,777,216 | Wb 294,912 | Wt0 1K | bp 1K | tsq 524,288 | ssbuf 1,048,576 (~18.6 MB)
  __hip_bfloat16* xs  = (__hip_bfloat16*)(ws);
  __hip_bfloat16* Wb  = (__hip_bfloat16*)(ws + 16777216);
  float*          Wt0 = (float*)(ws + 17072128);
  float*          bp  = (float*)(ws + 17073152);
  float*          tsq = (float*)(ws + 17074176);
  float*          ssb = (float*)(ws + 17598464);

  prep<<<4352, 256, 0, stream>>>(x, W, b, xs, tsq, Wb, Wt0, bp);
  hypconv_main<<<2048, 256, 0, stream>>>(tsq, xs, Wb, Wt0, bp, out, ssb);
  finalize_t<<<512, 256, 0, stream>>>(ssb, out);
}